// Round 1
// baseline (441.957 us; speedup 1.0000x reference)
//
#include <hip/hip_runtime.h>
#include <hip/hip_bf16.h>
#include <stdint.h>

// Problem constants
#define Bn  4
#define Nn  10000
#define KRn 5
#define KAn 8
#define Cn  32
#define On  64
#define Kk  2
#define RN  8                  // rotations = KA
#define KDIM (KRn*KAn*Cn)      // 1280
#define NCOL (RN*On)           // 512
#define MT  64                 // points per block
#define LDX 264                // LDS row stride (bf16 elems): 256 + 8 pad

typedef __attribute__((ext_vector_type(8))) short bf16x8;
typedef __attribute__((ext_vector_type(4))) float f32x4;

static __device__ __forceinline__ unsigned int bfpack2(float a, float b) {
  unsigned int ua = __builtin_bit_cast(unsigned int, a);
  unsigned int ub = __builtin_bit_cast(unsigned int, b);
  ua = (ua + 0x7FFFu + ((ua >> 16) & 1u)) >> 16;
  ub = (ub + 0x7FFFu + ((ub >> 16) & 1u)) >> 16;
  return ua | (ub << 16);
}
static __device__ __forceinline__ unsigned short bf1(float a) {
  unsigned int ua = __builtin_bit_cast(unsigned int, a);
  return (unsigned short)((ua + 0x7FFFu + ((ua >> 16) & 1u)) >> 16);
}

// Build W in B-fragment-ready layout:
//   W[(p,q,c),(r,o)] = sum_g kernels[g, p, (q+r)%8, o, c]
// stored as wfrag[sg (0..39)][t (0..31)][lane (0..63)][j (0..7)] bf16, where
//   k = sg*32 + (lane>>4)*8 + j   (k = (p*8+q)*32 + c)
//   col = t*16 + (lane&15)        (col = r*64 + o)
// Also bconst[o] = Kk * sum_{p,q} bias[p,q,o].
__global__ void prep_kernel(const float* __restrict__ kernels,
                            const float* __restrict__ bias,
                            unsigned short* __restrict__ wfrag,
                            float* __restrict__ bconst) {
  int tid = blockIdx.x * blockDim.x + threadIdx.x;
  if (tid < 40 * 32 * 64) {
    int l = tid & 63;
    int t = (tid >> 6) & 31;
    int s = tid >> 11;                 // 0..39
    int col = t * 16 + (l & 15);
    int r = col >> 6, o = col & 63;
    int kb = s * 32 + (l >> 4) * 8;
    unsigned short v[8];
#pragma unroll
    for (int j = 0; j < 8; ++j) {
      int k = kb + j;
      int p = k >> 8;
      int q = (k >> 5) & 7;
      int c = k & 31;
      int qr = (q + r) & 7;
      const float* k0 = kernels + (((p * KAn + qr) * On + o) * Cn + c);
      float sum = k0[0] + k0[KRn * KAn * On * Cn];   // g=0 + g=1
      v[j] = bf1(sum);
    }
    reinterpret_cast<bf16x8*>(wfrag)[tid] = *reinterpret_cast<const bf16x8*>(v);
  }
  if (blockIdx.x == 0 && threadIdx.x < On) {
    float s = 0.f;
    for (int pq = 0; pq < KRn * KAn; ++pq) s += bias[pq * On + (int)threadIdx.x];
    bconst[threadIdx.x] = (float)Kk * s;
  }
}

// Main fused kernel: gather+interp into LDS (bf16), then MFMA GEMM.
__global__ __launch_bounds__(256, 2) void conv_kernel(
    const float* __restrict__ signal,
    const float* __restrict__ bary,
    const unsigned short* __restrict__ wfrag,
    const float* __restrict__ bconst,
    float* __restrict__ out) {
  __shared__ __align__(16) unsigned short xs[MT * LDX];

  const int b    = blockIdx.y;
  const int m0   = blockIdx.x * MT;
  const int tid  = threadIdx.x;
  const int lane = tid & 63;
  const int wv   = tid >> 6;           // wave 0..3

  f32x4 acc[4][8];
#pragma unroll
  for (int m = 0; m < 4; ++m)
#pragma unroll
    for (int j = 0; j < 8; ++j) acc[m][j] = (f32x4){0.f, 0.f, 0.f, 0.f};

  const float* sigb  = signal + (size_t)b * Nn * Cn;
  const float* baryb = bary   + (size_t)b * Nn * (KRn * KAn * 3 * 2);
  const bf16x8* wf   = reinterpret_cast<const bf16x8*>(wfrag);

  const int lm  = lane & 15;           // row-in-tile / col-in-tile
  const int lg  = lane >> 4;           // 0..3 lane group

  for (int p = 0; p < KRn; ++p) {
    __syncthreads();  // previous chunk's reads done before overwrite
    // ---- stage: interp for chunk p -> xs[64][256] bf16 ----
#pragma unroll
    for (int half = 0; half < 2; ++half) {
      int pair = tid + half * 256;     // 0..511 = 64 points x 8 q
      int pt = pair >> 3;
      int q  = pair & 7;
      int n  = m0 + pt;
      unsigned short* xrow = xs + pt * LDX + q * 32;
      if (n < Nn) {
        const float* bp = baryb + ((size_t)(n * (KRn * KAn) + p * KAn + q)) * 6;
        float i0f = bp[0], w0 = bp[1];
        float i1f = bp[2], w1 = bp[3];
        float i2f = bp[4], w2 = bp[5];
        int i0 = (int)i0f, i1 = (int)i1f, i2 = (int)i2f;
        const f32x4* s0 = reinterpret_cast<const f32x4*>(sigb + i0 * Cn);
        const f32x4* s1 = reinterpret_cast<const f32x4*>(sigb + i1 * Cn);
        const f32x4* s2 = reinterpret_cast<const f32x4*>(sigb + i2 * Cn);
#pragma unroll
        for (int cv = 0; cv < 8; ++cv) {
          f32x4 v = w0 * s0[cv] + w1 * s1[cv] + w2 * s2[cv];
          unsigned long long pk =
              (unsigned long long)bfpack2(v.x, v.y) |
              ((unsigned long long)bfpack2(v.z, v.w) << 32);
          *reinterpret_cast<unsigned long long*>(xrow + cv * 4) = pk;
        }
      } else {
#pragma unroll
        for (int cv = 0; cv < 8; ++cv)
          *reinterpret_cast<unsigned long long*>(xrow + cv * 4) = 0ull;
      }
    }
    __syncthreads();
    // ---- GEMM: 8 k-steps of 32 over this chunk ----
    for (int ks = 0; ks < 8; ++ks) {
      int sg = p * 8 + ks;
      bf16x8 a[4];
#pragma unroll
      for (int mt = 0; mt < 4; ++mt)
        a[mt] = *reinterpret_cast<const bf16x8*>(
            xs + (mt * 16 + lm) * LDX + ks * 32 + lg * 8);
#pragma unroll
      for (int j = 0; j < 8; ++j) {
        int t = wv * 8 + j;
        bf16x8 bfr = wf[(sg * 32 + t) * 64 + lane];
#pragma unroll
        for (int mt = 0; mt < 4; ++mt)
          acc[mt][j] = __builtin_amdgcn_mfma_f32_16x16x32_bf16(
              a[mt], bfr, acc[mt][j], 0, 0, 0);
      }
    }
  }

  // ---- epilogue: out[b, r, n, o] = acc + bconst[o] ----
#pragma unroll
  for (int j = 0; j < 8; ++j) {
    int t   = wv * 8 + j;
    int col = t * 16 + lm;             // = r*64 + o
    int r   = col >> 6;
    int o   = col & 63;
    float bc = bconst[o];
    float* outp = out + (((size_t)b * RN + r) * Nn) * On + o;
#pragma unroll
    for (int mt = 0; mt < 4; ++mt) {
      int nbase = m0 + mt * 16 + lg * 4;
#pragma unroll
      for (int i = 0; i < 4; ++i) {
        int n = nbase + i;
        if (n < Nn) outp[(size_t)n * On] = acc[mt][j][i] + bc;
      }
    }
  }
}

extern "C" void kernel_launch(void* const* d_in, const int* in_sizes, int n_in,
                              void* d_out, int out_size, void* d_ws, size_t ws_size,
                              hipStream_t stream) {
  const float* signal  = (const float*)d_in[0];
  const float* bary    = (const float*)d_in[1];
  const float* kernels = (const float*)d_in[2];
  const float* bias    = (const float*)d_in[3];
  float* out = (float*)d_out;

  unsigned short* wfrag = (unsigned short*)d_ws;
  float* bconst = (float*)((char*)d_ws + (size_t)KDIM * NCOL * 2);

  hipLaunchKernelGGL(prep_kernel, dim3(320), dim3(256), 0, stream,
                     kernels, bias, wfrag, bconst);
  dim3 grid((Nn + MT - 1) / MT, Bn);
  hipLaunchKernelGGL(conv_kernel, grid, dim3(256), 0, stream,
                     signal, bary, wfrag, bconst, out);
}

// Round 2
// 330.344 us; speedup vs baseline: 1.3379x; 1.3379x over previous
//
#include <hip/hip_runtime.h>
#include <hip/hip_bf16.h>
#include <stdint.h>

// Problem constants
#define Bn  4
#define Nn  10000
#define KRn 5
#define KAn 8
#define Cn  32
#define On  64
#define Kk  2
#define RN  8                  // rotations = KA
#define MT  32                 // points per block
#define LDX 264                // LDS row stride (bf16 elems): 256 + 8 pad (2-way max, free)

typedef __attribute__((ext_vector_type(8))) short bf16x8;
typedef __attribute__((ext_vector_type(4))) float f32x4;

static __device__ __forceinline__ unsigned int bfpack2(float a, float b) {
  unsigned int ua = __builtin_bit_cast(unsigned int, a);
  unsigned int ub = __builtin_bit_cast(unsigned int, b);
  ua = (ua + 0x7FFFu + ((ua >> 16) & 1u)) >> 16;
  ub = (ub + 0x7FFFu + ((ub >> 16) & 1u)) >> 16;
  return ua | (ub << 16);
}
static __device__ __forceinline__ unsigned short bf1(float a) {
  unsigned int ua = __builtin_bit_cast(unsigned int, a);
  return (unsigned short)((ua + 0x7FFFu + ((ua >> 16) & 1u)) >> 16);
}

// Un-rotated summed kernel, B-fragment-ready:
//   wk[p][q'][ot][lane][j] = sum_g kernels[g, p, q', o, c]
//   o = ot*16 + (lane&15), c = (lane>>4)*8 + j
// Total 5*8*4*64*8 bf16 = 160 KB (8x smaller than materializing rotations;
// the rotation becomes index arithmetic q = (q' - r) & 7 in the GEMM loop).
__global__ void prep_kernel(const float* __restrict__ kernels,
                            const float* __restrict__ bias,
                            unsigned short* __restrict__ wk,
                            float* __restrict__ bconst) {
  int tid = blockIdx.x * 256 + threadIdx.x;
  if (tid < KRn * KAn * 4 * 64) {
    int lane = tid & 63;
    int ot   = (tid >> 6) & 3;
    int q    = (tid >> 8) & 7;
    int p    = tid >> 11;
    int o  = ot * 16 + (lane & 15);
    int cb = (lane >> 4) * 8;
    const float* k0 = kernels + (((p * KAn + q) * On + o) * Cn + cb);
    const float* k1 = k0 + KRn * KAn * On * Cn;  // g=1
    unsigned short v[8];
#pragma unroll
    for (int j = 0; j < 8; ++j) v[j] = bf1(k0[j] + k1[j]);
    reinterpret_cast<bf16x8*>(wk)[tid] = *reinterpret_cast<const bf16x8*>(v);
  }
  if (blockIdx.x == 0 && threadIdx.x < On) {
    float s = 0.f;
    for (int pq = 0; pq < KRn * KAn; ++pq) s += bias[pq * On + (int)threadIdx.x];
    bconst[threadIdx.x] = (float)Kk * s;
  }
}

// Fused gather+interp (LDS, double-buffered) + MFMA GEMM with rotation-by-index.
__global__ __launch_bounds__(256, 4) void conv_kernel(
    const float* __restrict__ signal,
    const float* __restrict__ bary,
    const unsigned short* __restrict__ wk,
    const float* __restrict__ bconst,
    float* __restrict__ out) {
  __shared__ __align__(16) unsigned short xs[2][MT * LDX];  // 2 x 16.9 KB

  const int b    = blockIdx.y;
  const int m0   = blockIdx.x * MT;
  const int tid  = threadIdx.x;
  const int lane = tid & 63;
  const int wv   = tid >> 6;           // wave 0..3
  const int lm   = lane & 15;
  const int lg   = lane >> 4;

  f32x4 acc[2][4][2];                  // [rr][ot][mt]
#pragma unroll
  for (int rr = 0; rr < 2; ++rr)
#pragma unroll
    for (int ot = 0; ot < 4; ++ot)
#pragma unroll
      for (int mt = 0; mt < 2; ++mt) acc[rr][ot][mt] = (f32x4){0.f, 0.f, 0.f, 0.f};

  const float* sigb  = signal + (size_t)b * Nn * Cn;
  const float* baryb = bary   + (size_t)b * Nn * (KRn * KAn * 3 * 2);
  const bf16x8* wkf  = reinterpret_cast<const bf16x8*>(wk);

  // staging identity: one (point, q) pair per thread
  const int pt   = tid >> 3;           // 0..31
  const int sq   = tid & 7;            // 0..7
  const int n_st = m0 + pt;
  const bool valid = n_st < Nn;
  const float* bpt = baryb + ((size_t)n_st * (KRn * KAn) + sq) * 6;

#define INTERP_WRITE(BUF, B0, B1, B2, B3, B4, B5)                              \
  {                                                                            \
    unsigned short* xrow = &xs[BUF][pt * LDX + sq * 32];                       \
    if (valid) {                                                               \
      int i0 = (int)(B0), i1 = (int)(B2), i2 = (int)(B4);                      \
      float w0 = (B1), w1 = (B3), w2 = (B5);                                   \
      const f32x4* s0 = (const f32x4*)(sigb + (size_t)i0 * Cn);                \
      const f32x4* s1 = (const f32x4*)(sigb + (size_t)i1 * Cn);                \
      const f32x4* s2 = (const f32x4*)(sigb + (size_t)i2 * Cn);                \
      _Pragma("unroll")                                                        \
      for (int cv = 0; cv < 8; ++cv) {                                         \
        int cs = (cv + sq) & 7; /* rotated order: conflict-free LDS writes */  \
        f32x4 v = w0 * s0[cs] + w1 * s1[cs] + w2 * s2[cs];                     \
        unsigned long long pk = (unsigned long long)bfpack2(v.x, v.y) |        \
                                ((unsigned long long)bfpack2(v.z, v.w) << 32); \
        *(unsigned long long*)(xrow + cs * 4) = pk;                            \
      }                                                                        \
    } else {                                                                   \
      _Pragma("unroll")                                                        \
      for (int cv = 0; cv < 8; ++cv)                                           \
        *(unsigned long long*)(xrow + cv * 4) = 0ull;                          \
    }                                                                          \
  }

  // prologue: stage chunk 0
  {
    float b0 = 0, b1 = 0, b2 = 0, b3 = 0, b4 = 0, b5 = 0;
    if (valid) {
      const float* bp = bpt;
      b0 = bp[0]; b1 = bp[1]; b2 = bp[2]; b3 = bp[3]; b4 = bp[4]; b5 = bp[5];
    }
    INTERP_WRITE(0, b0, b1, b2, b3, b4, b5);
  }

  for (int p = 0; p < KRn; ++p) {
    __syncthreads();                   // buf[p&1] staged by all waves
    const int pb = p & 1;
    const bool more = (p + 1 < KRn);

    // issue next chunk's barycentric loads BEFORE the MFMA phase (latency hides)
    float b0 = 0, b1 = 0, b2 = 0, b3 = 0, b4 = 0, b5 = 0;
    if (more && valid) {
      const float* bp = bpt + (p + 1) * (KAn * 6);
      b0 = bp[0]; b1 = bp[1]; b2 = bp[2]; b3 = bp[3]; b4 = bp[4]; b5 = bp[5];
    }

    // ---- GEMM on chunk p: loop over q' with rotation-by-index ----
#pragma unroll 2
    for (int qp = 0; qp < 8; ++qp) {
      const bf16x8* wkp = wkf + ((size_t)(p * 8 + qp) * 4) * 64 + lane;
      bf16x8 Bf[4];
#pragma unroll
      for (int ot = 0; ot < 4; ++ot) Bf[ot] = wkp[ot * 64];  // L1-hot, wave-shared
#pragma unroll
      for (int rr = 0; rr < 2; ++rr) {
        int r = wv * 2 + rr;
        int q = (qp - r) & 7;          // rotation: A chunk q feeds output ring r
#pragma unroll
        for (int mt = 0; mt < 2; ++mt) {
          bf16x8 a = *(const bf16x8*)(&xs[pb][(mt * 16 + lm) * LDX + q * 32 + lg * 8]);
#pragma unroll
          for (int ot = 0; ot < 4; ++ot)
            acc[rr][ot][mt] = __builtin_amdgcn_mfma_f32_16x16x32_bf16(
                a, Bf[ot], acc[rr][ot][mt], 0, 0, 0);
        }
      }
    }

    // ---- finish staging chunk p+1 into the other buffer ----
    if (more) INTERP_WRITE(pb ^ 1, b0, b1, b2, b3, b4, b5);
  }

  // ---- epilogue: out[b, r, n, o] += bconst ----
#pragma unroll
  for (int rr = 0; rr < 2; ++rr) {
    int r = wv * 2 + rr;
#pragma unroll
    for (int ot = 0; ot < 4; ++ot) {
      int o = ot * 16 + lm;
      float bc = bconst[o];
      float* outp = out + (((size_t)b * RN + r) * Nn) * On + o;
#pragma unroll
      for (int mt = 0; mt < 2; ++mt) {
        int nbase = m0 + mt * 16 + lg * 4;
#pragma unroll
        for (int i = 0; i < 4; ++i) {
          int n = nbase + i;
          if (n < Nn) outp[(size_t)n * On] = acc[rr][ot][mt][i] + bc;
        }
      }
    }
  }
#undef INTERP_WRITE
}

extern "C" void kernel_launch(void* const* d_in, const int* in_sizes, int n_in,
                              void* d_out, int out_size, void* d_ws, size_t ws_size,
                              hipStream_t stream) {
  const float* signal  = (const float*)d_in[0];
  const float* bary    = (const float*)d_in[1];
  const float* kernels = (const float*)d_in[2];
  const float* bias    = (const float*)d_in[3];
  float* out = (float*)d_out;

  unsigned short* wk = (unsigned short*)d_ws;
  float* bconst = (float*)((char*)d_ws + (size_t)KRn * KAn * 4 * 64 * 8 * 2);

  hipLaunchKernelGGL(prep_kernel, dim3(40), dim3(256), 0, stream,
                     kernels, bias, wk, bconst);
  dim3 grid((Nn + MT - 1) / MT, Bn);
  hipLaunchKernelGGL(conv_kernel, grid, dim3(256), 0, stream,
                     signal, bary, wk, bconst, out);
}

// Round 3
// 192.721 us; speedup vs baseline: 2.2932x; 1.7141x over previous
//
#include <hip/hip_runtime.h>
#include <hip/hip_bf16.h>
#include <stdint.h>

// Problem constants
#define Bn  4
#define Nn  10000
#define KRn 5
#define KAn 8
#define Cn  32
#define On  64
#define Kk  2
#define RN  8                  // rotations = KA
#define MT  32                 // points per block
#define LDX 264                // LDS row stride (bf16 elems): 256 + 8 pad

typedef __attribute__((ext_vector_type(8))) short bf16x8;
typedef __attribute__((ext_vector_type(4))) float f32x4;
typedef __attribute__((ext_vector_type(2))) float f32x2;

static __device__ __forceinline__ unsigned int bfpack2(float a, float b) {
  unsigned int ua = __builtin_bit_cast(unsigned int, a);
  unsigned int ub = __builtin_bit_cast(unsigned int, b);
  ua = (ua + 0x7FFFu + ((ua >> 16) & 1u)) >> 16;
  ub = (ub + 0x7FFFu + ((ub >> 16) & 1u)) >> 16;
  return ua | (ub << 16);
}
static __device__ __forceinline__ unsigned short bf1(float a) {
  unsigned int ua = __builtin_bit_cast(unsigned int, a);
  return (unsigned short)((ua + 0x7FFFu + ((ua >> 16) & 1u)) >> 16);
}

// Un-rotated summed kernel, B-fragment-ready:
//   wk[p][q'][ot][lane][j] = sum_g kernels[g, p, q', o, c]
//   o = ot*16 + (lane&15), c = (lane>>4)*8 + j
__global__ void prep_kernel(const float* __restrict__ kernels,
                            const float* __restrict__ bias,
                            unsigned short* __restrict__ wk,
                            float* __restrict__ bconst) {
  int tid = blockIdx.x * 256 + threadIdx.x;
  if (tid < KRn * KAn * 4 * 64) {
    int lane = tid & 63;
    int ot   = (tid >> 6) & 3;
    int q    = (tid >> 8) & 7;
    int p    = tid >> 11;
    int o  = ot * 16 + (lane & 15);
    int cb = (lane >> 4) * 8;
    const float* k0 = kernels + (((p * KAn + q) * On + o) * Cn + cb);
    const float* k1 = k0 + KRn * KAn * On * Cn;  // g=1
    unsigned short v[8];
#pragma unroll
    for (int j = 0; j < 8; ++j) v[j] = bf1(k0[j] + k1[j]);
    reinterpret_cast<bf16x8*>(wk)[tid] = *reinterpret_cast<const bf16x8*>(v);
  }
  if (blockIdx.x == 0 && threadIdx.x < On) {
    float s = 0.f;
    for (int pq = 0; pq < KRn * KAn; ++pq) s += bias[pq * On + (int)threadIdx.x];
    bconst[threadIdx.x] = (float)Kk * s;
  }
}

// Fused gather+interp (group-coalesced) + MFMA GEMM with rotation-by-index.
__global__ __launch_bounds__(256, 4) void conv_kernel(
    const float* __restrict__ signal,
    const float* __restrict__ bary,
    const unsigned short* __restrict__ wk,
    const float* __restrict__ bconst,
    float* __restrict__ out) {
  __shared__ __align__(16) unsigned short xs[2][MT * LDX];  // 2 x 16.5 KB
  __shared__ __align__(16) float bs[MT * 48];               // bary chunk: 6 KB

  const int b    = blockIdx.y;
  const int m0   = blockIdx.x * MT;
  const int tid  = threadIdx.x;
  const int lane = tid & 63;
  const int wv   = tid >> 6;           // wave 0..3
  const int lm   = lane & 15;
  const int lg   = lane >> 4;

  f32x4 acc[2][4][2];                  // [rr][ot][mt]
#pragma unroll
  for (int rr = 0; rr < 2; ++rr)
#pragma unroll
    for (int ot = 0; ot < 4; ++ot)
#pragma unroll
      for (int mt = 0; mt < 2; ++mt) acc[rr][ot][mt] = (f32x4){0.f, 0.f, 0.f, 0.f};

  const float* sigb  = signal + (size_t)b * Nn * Cn;
  const bf16x8* wkf  = reinterpret_cast<const bf16x8*>(wk);

  // ---- staging identities ----
  // interp: 8-lane group owns one (pt, q); lane cv handles channels cv*4..cv*4+3
  const int sq = lane >> 3;            // q of this group
  const int cv = lane & 7;             // channel-vec within row
  // bary stage: thread (bpt, bc8) loads 6 contiguous floats
  const int bpt = tid >> 3;            // 0..31 point
  const int bc8 = tid & 7;             // 0..7  q
  const int bn  = m0 + bpt;
  const bool bvalid = bn < Nn;
  const float* bybase = bary + (size_t)b * Nn * 240 + (size_t)bn * 240 + bc8 * 6;

  f32x2 br0, br1, br2;                 // bary prefetch regs

#define LOAD_BARY(PP)                                                          \
  if (bvalid) {                                                                \
    const float* src = bybase + (PP) * 48;                                     \
    br0 = *(const f32x2*)(src);                                                \
    br1 = *(const f32x2*)(src + 2);                                            \
    br2 = *(const f32x2*)(src + 4);                                            \
  } else {                                                                     \
    br0 = (f32x2){0.f, 0.f}; br1 = br0; br2 = br0;                             \
  }

#define WRITE_BARY()                                                           \
  {                                                                            \
    float* d = &bs[bpt * 48 + bc8 * 6];                                        \
    *(f32x2*)(d)     = br0;                                                    \
    *(f32x2*)(d + 2) = br1;                                                    \
    *(f32x2*)(d + 4) = br2;                                                    \
  }

  // interp chunk -> xs[WB]; zeroed bs rows give zero interp for tail points
#define INTERP(WB)                                                             \
  _Pragma("unroll")                                                            \
  for (int k = 0; k < 8; ++k) {                                                \
    int pt = k * 4 + wv;                                                       \
    const float* bb = &bs[pt * 48 + sq * 6];                                   \
    f32x2 p0 = *(const f32x2*)(bb);                                            \
    f32x2 p1 = *(const f32x2*)(bb + 2);                                        \
    f32x2 p2 = *(const f32x2*)(bb + 4);                                        \
    int i0 = (int)p0.x, i1 = (int)p1.x, i2 = (int)p2.x;                        \
    f32x4 s0 = *(const f32x4*)(sigb + (size_t)i0 * Cn + cv * 4);               \
    f32x4 s1 = *(const f32x4*)(sigb + (size_t)i1 * Cn + cv * 4);               \
    f32x4 s2 = *(const f32x4*)(sigb + (size_t)i2 * Cn + cv * 4);               \
    f32x4 v = p0.y * s0 + p1.y * s1 + p2.y * s2;                               \
    unsigned long long pk = (unsigned long long)bfpack2(v.x, v.y) |            \
                            ((unsigned long long)bfpack2(v.z, v.w) << 32);     \
    *(unsigned long long*)(&xs[WB][pt * LDX + sq * 32 + cv * 4]) = pk;         \
  }

  // ---- prologue: bary chunk 0 -> bs, interp chunk 0 -> xs[0] ----
  LOAD_BARY(0);
  WRITE_BARY();
  __syncthreads();
  INTERP(0);

  for (int p = 0; p < KRn; ++p) {
    __syncthreads();                   // xs[p&1] fully staged
    const int pb = p & 1;
    const bool more = (p + 1 < KRn);
    if (more) { LOAD_BARY(p + 1); }    // latency hides under GEMM

    // ---- GEMM on chunk p: loop over q' with rotation-by-index ----
#pragma unroll 2
    for (int qp = 0; qp < 8; ++qp) {
      const bf16x8* wkp = wkf + ((size_t)(p * 8 + qp) * 4) * 64 + lane;
      bf16x8 Bf[4];
#pragma unroll
      for (int ot = 0; ot < 4; ++ot) Bf[ot] = wkp[ot * 64];
#pragma unroll
      for (int rr = 0; rr < 2; ++rr) {
        int r = wv * 2 + rr;
        int q = (qp - r) & 7;          // rotation: A chunk q feeds output ring r
#pragma unroll
        for (int mt = 0; mt < 2; ++mt) {
          bf16x8 a = *(const bf16x8*)(&xs[pb][(mt * 16 + lm) * LDX + q * 32 + lg * 8]);
#pragma unroll
          for (int ot = 0; ot < 4; ++ot)
            acc[rr][ot][mt] = __builtin_amdgcn_mfma_f32_16x16x32_bf16(
                a, Bf[ot], acc[rr][ot][mt], 0, 0, 0);
        }
      }
    }

    if (more) {
      WRITE_BARY();
      __syncthreads();                 // bs visible to all waves
      INTERP(pb ^ 1);
    }
  }

  // ---- epilogue: out[b, r, n, o] = acc + bconst[o] ----
#pragma unroll
  for (int rr = 0; rr < 2; ++rr) {
    int r = wv * 2 + rr;
#pragma unroll
    for (int ot = 0; ot < 4; ++ot) {
      int o = ot * 16 + lm;
      float bc = bconst[o];
      float* outp = out + (((size_t)b * RN + r) * Nn) * On + o;
#pragma unroll
      for (int mt = 0; mt < 2; ++mt) {
        int nbase = m0 + mt * 16 + lg * 4;
#pragma unroll
        for (int i = 0; i < 4; ++i) {
          int n = nbase + i;
          if (n < Nn) outp[(size_t)n * On] = acc[rr][ot][mt][i] + bc;
        }
      }
    }
  }
#undef LOAD_BARY
#undef WRITE_BARY
#undef INTERP
}

extern "C" void kernel_launch(void* const* d_in, const int* in_sizes, int n_in,
                              void* d_out, int out_size, void* d_ws, size_t ws_size,
                              hipStream_t stream) {
  const float* signal  = (const float*)d_in[0];
  const float* bary    = (const float*)d_in[1];
  const float* kernels = (const float*)d_in[2];
  const float* bias    = (const float*)d_in[3];
  float* out = (float*)d_out;

  unsigned short* wk = (unsigned short*)d_ws;
  float* bconst = (float*)((char*)d_ws + (size_t)KRn * KAn * 4 * 64 * 8 * 2);

  hipLaunchKernelGGL(prep_kernel, dim3(40), dim3(256), 0, stream,
                     kernels, bias, wk, bconst);
  dim3 grid((Nn + MT - 1) / MT, Bn);
  hipLaunchKernelGGL(conv_kernel, grid, dim3(256), 0, stream,
                     signal, bary, wk, bconst, out);
}